// Round 1
// baseline (14304.953 us; speedup 1.0000x reference)
//
#include <hip/hip_runtime.h>

// Problem constants (from reference): B=512 T=512 I=128 H=512 C=128 OUT_T=128
#define Bq 512
#define Tq 512
#define Iq 128
#define Hq 512
#define Cq 128
#define OUT_Tq 128
#define Gq 4   // batches per block

// ---- workspace layout (float offsets) ----
// wt_enc : [160][512][4]  (k=0..639 transposed; k<128 from W_ih, else W_hh)   327680 floats
// wt_fc1 : [128][512][4]                                                      262144 floats
// wt_fc2 : [128][128][4]                                                       65536 floats
// cbias  : [512]  (b_ih + b_hh)                                                 512 floats
#define OFF_WTENC 0
#define OFF_WTFC1 327680
#define OFF_WTFC2 589824
#define OFF_CBIAS 655360

__global__ void prep_enc(const float* __restrict__ W_ih, const float* __restrict__ W_hh,
                         float* __restrict__ wt) {
    int idx = blockIdx.x * 256 + threadIdx.x;           // over 512*640
    if (idx >= 512 * 640) return;
    int n = idx / 640, k = idx % 640;
    float v = (k < Iq) ? W_ih[n * Iq + k] : W_hh[n * Hq + (k - Iq)];
    wt[(k >> 2) * 2048 + n * 4 + (k & 3)] = v;
}

__global__ void prep_fc1(const float* __restrict__ W, float* __restrict__ wt) {
    int idx = blockIdx.x * 256 + threadIdx.x;           // over 512*512
    if (idx >= 512 * 512) return;
    int n = idx >> 9, k = idx & 511;
    wt[(k >> 2) * 2048 + n * 4 + (k & 3)] = W[n * Hq + k];
}

__global__ void prep_fc2(const float* __restrict__ W, float* __restrict__ wt) {
    int idx = blockIdx.x * 256 + threadIdx.x;           // over 128*512
    if (idx >= 128 * 512) return;
    int c = idx >> 9, k = idx & 511;
    wt[(k >> 2) * 512 + c * 4 + (k & 3)] = W[c * Hq + k];
}

__global__ void prep_bias(const float* __restrict__ bih, const float* __restrict__ bhh,
                          float* __restrict__ cb) {
    int n = blockIdx.x * 256 + threadIdx.x;
    if (n < Hq) cb[n] = bih[n] + bhh[n];
}

__device__ __forceinline__ float dot4(float4 w, float4 v) {
    return w.x * v.x + w.y * v.y + w.z * v.z + w.w * v.w;
}

// 1024 threads: n = tid&511 (output neuron), kh = tid>>9 (k-split half).
// k-split shares the weight stream between halves (no extra L2 traffic) and
// doubles resident waves (16/CU = 4/SIMD) for latency hiding.
// __launch_bounds__(1024,4): VGPR budget 128 (vs 60 before) -> real ILP.
__global__ void __launch_bounds__(1024, 4)
rnn_fused(const float* __restrict__ x, const int* __restrict__ lengths,
          const float* __restrict__ wt_enc, const float* __restrict__ wt_fc1,
          const float* __restrict__ wt_fc2, const float* __restrict__ cbias,
          const float* __restrict__ fc1_b, const float* __restrict__ fc2_b,
          float* __restrict__ out) {
    __shared__ __align__(16) float in_s[Gq][Iq + Hq];   // [x_t | h]   10240 B
    __shared__ __align__(16) float mid_s[Gq][Hq];       //              8192 B
    __shared__ __align__(16) float sc[Gq * Hq];         // k-split partials 8192 B
    __shared__ __align__(16) float ps[1024];            // fc2 partials 4096 B

    const int tid = threadIdx.x;          // 0..1023
    const int n   = tid & 511;
    const int kh  = tid >> 9;             // 0 or 1: which k-half
    const int gb0 = blockIdx.x * Gq;

    const int len0 = lengths[gb0 + 0];
    const int len1 = lengths[gb0 + 1];
    const int len2 = lengths[gb0 + 2];
    const int len3 = lengths[gb0 + 3];
    const int tmax = max(max(len0, len1), max(len2, len3));

    const int b8 = (tid >> 7) & 3;        // kh==1 staging role: batch
    const int i8 = tid & 127;             //                     element

    // h = 0 (kh0 half); stage x(0) (kh1 half)
    if (kh == 0) {
        in_s[0][Iq + n] = 0.f; in_s[1][Iq + n] = 0.f;
        in_s[2][Iq + n] = 0.f; in_s[3][Iq + n] = 0.f;
    } else if (tmax > 0) {
        in_s[b8][i8] = x[(size_t)(gb0 + b8) * Tq * Iq + i8];
    }

    const float4* We = (const float4*)wt_enc;           // [160][512]
    const float cb = cbias[n];
    const int k0beg = kh * 80;                          // this half's k0 range

    // ---------------- encoder ----------------
    for (int t = 0; t < tmax; ++t) {
        __syncthreads();                  // publish x(t) and h(t-1)
        // prefetch x(t+1) into regs; hides under the dot-product loop
        float xr = 0.f;
        if (kh == 1 && t + 1 < tmax)
            xr = x[(size_t)(gb0 + b8) * Tq * Iq + (size_t)(t + 1) * Iq + i8];

        float a0 = 0.f, a1 = 0.f, a2 = 0.f, a3 = 0.f;
#pragma unroll 4
        for (int j = 0; j < 80; ++j) {
            int k0 = k0beg + j;
            float4 w  = We[k0 * 512 + n];                 // coalesced dwordx4
            float4 i0 = *(const float4*)&in_s[0][k0 * 4]; // LDS broadcast
            float4 i1 = *(const float4*)&in_s[1][k0 * 4];
            float4 i2 = *(const float4*)&in_s[2][k0 * 4];
            float4 i3 = *(const float4*)&in_s[3][k0 * 4];
            a0 += dot4(w, i0); a1 += dot4(w, i1);
            a2 += dot4(w, i2); a3 += dot4(w, i3);
        }
        if (kh == 1) {
            sc[0 * 512 + n] = a0; sc[1 * 512 + n] = a1;
            sc[2 * 512 + n] = a2; sc[3 * 512 + n] = a3;
        }
        __syncthreads();                  // partials ready; all in_s reads done
        if (kh == 0) {
            float nh0 = tanhf(a0 + sc[0 * 512 + n] + cb);
            float nh1 = tanhf(a1 + sc[1 * 512 + n] + cb);
            float nh2 = tanhf(a2 + sc[2 * 512 + n] + cb);
            float nh3 = tanhf(a3 + sc[3 * 512 + n] + cb);
            if (t < len0) in_s[0][Iq + n] = nh0;
            if (t < len1) in_s[1][Iq + n] = nh1;
            if (t < len2) in_s[2][Iq + n] = nh2;
            if (t < len3) in_s[3][Iq + n] = nh3;
        } else {
            if (t + 1 < tmax) in_s[b8][i8] = xr;   // disjoint from h region
        }
        // next-iter top barrier publishes both
    }
    __syncthreads();

    // ---------------- decoder ----------------
    const float4* Wd = We + 32 * 512;                   // W_hh^T rows (k0 = 0..127)
    const float4* W1 = (const float4*)wt_fc1;
    const float4* W2 = (const float4*)wt_fc2;
    const float f1b = fc1_b[n];
    const int bq = n >> 7, c = n & 127;                 // fc2 output mapping
    const float f2b = fc2_b[c];
    const int k0d = kh * 64;                            // k-half for 128-chunk dots

    for (int t = 0; t < OUT_Tq; ++t) {
        // phase 1: nh = tanh(cbias + h @ W_hh^T)
        float a0 = 0.f, a1 = 0.f, a2 = 0.f, a3 = 0.f;
#pragma unroll 4
        for (int j = 0; j < 64; ++j) {
            int k0 = k0d + j;
            float4 w  = Wd[k0 * 512 + n];
            float4 h0 = *(const float4*)&in_s[0][Iq + k0 * 4];
            float4 h1 = *(const float4*)&in_s[1][Iq + k0 * 4];
            float4 h2 = *(const float4*)&in_s[2][Iq + k0 * 4];
            float4 h3 = *(const float4*)&in_s[3][Iq + k0 * 4];
            a0 += dot4(w, h0); a1 += dot4(w, h1);
            a2 += dot4(w, h2); a3 += dot4(w, h3);
        }
        if (kh == 1) {
            sc[n] = a0; sc[512 + n] = a1; sc[1024 + n] = a2; sc[1536 + n] = a3;
        }
        __syncthreads();   // A: partials ready, h reads done
        if (kh == 0) {
            in_s[0][Iq + n] = tanhf(a0 + sc[n]        + cb);
            in_s[1][Iq + n] = tanhf(a1 + sc[512 + n]  + cb);
            in_s[2][Iq + n] = tanhf(a2 + sc[1024 + n] + cb);
            in_s[3][Iq + n] = tanhf(a3 + sc[1536 + n] + cb);
        }
        __syncthreads();   // B: new h published
        // phase 2: mid = relu(nh @ fc1^T + fc1_b)
        a0 = a1 = a2 = a3 = 0.f;
#pragma unroll 4
        for (int j = 0; j < 64; ++j) {
            int k0 = k0d + j;
            float4 w  = W1[k0 * 512 + n];
            float4 h0 = *(const float4*)&in_s[0][Iq + k0 * 4];
            float4 h1 = *(const float4*)&in_s[1][Iq + k0 * 4];
            float4 h2 = *(const float4*)&in_s[2][Iq + k0 * 4];
            float4 h3 = *(const float4*)&in_s[3][Iq + k0 * 4];
            a0 += dot4(w, h0); a1 += dot4(w, h1);
            a2 += dot4(w, h2); a3 += dot4(w, h3);
        }
        if (kh == 1) {
            sc[n] = a0; sc[512 + n] = a1; sc[1024 + n] = a2; sc[1536 + n] = a3;
        }
        __syncthreads();   // C
        if (kh == 0) {
            mid_s[0][n] = fmaxf(a0 + sc[n]        + f1b, 0.f);
            mid_s[1][n] = fmaxf(a1 + sc[512 + n]  + f1b, 0.f);
            mid_s[2][n] = fmaxf(a2 + sc[1024 + n] + f1b, 0.f);
            mid_s[3][n] = fmaxf(a3 + sc[1536 + n] + f1b, 0.f);
        }
        __syncthreads();   // D: mid published
        // phase 3: out = mid @ fc2^T + fc2_b  (2 threads per output, k-split)
        float ao = 0.f;
#pragma unroll 4
        for (int j = 0; j < 64; ++j) {
            int k0 = k0d + j;
            float4 w = W2[k0 * 128 + c];
            float4 m = *(const float4*)&mid_s[bq][k0 * 4];
            ao += dot4(w, m);
        }
        ps[tid] = ao;
        __syncthreads();   // E: fc2 partials ready
        if (kh == 0)
            out[((size_t)(gb0 + bq) * OUT_Tq + t) * Cq + c] = ps[tid] + ps[tid + 512] + f2b;
        // no trailing barrier needed: next write to ps is after next iter's A..D
    }
}

extern "C" void kernel_launch(void* const* d_in, const int* in_sizes, int n_in,
                              void* d_out, int out_size, void* d_ws, size_t ws_size,
                              hipStream_t stream) {
    const float* x      = (const float*)d_in[0];
    const int*   lens   = (const int*)d_in[1];
    // d_in[2] = out_lengths (constant 128, hardcoded)
    const float* W_ih   = (const float*)d_in[3];
    const float* W_hh   = (const float*)d_in[4];
    const float* b_ih   = (const float*)d_in[5];
    const float* b_hh   = (const float*)d_in[6];
    const float* fc1_W  = (const float*)d_in[7];
    const float* fc1_b  = (const float*)d_in[8];
    const float* fc2_W  = (const float*)d_in[9];
    const float* fc2_b  = (const float*)d_in[10];

    float* ws   = (float*)d_ws;
    float* wtE  = ws + OFF_WTENC;
    float* wt1  = ws + OFF_WTFC1;
    float* wt2  = ws + OFF_WTFC2;
    float* cb   = ws + OFF_CBIAS;

    prep_enc <<<1280, 256, 0, stream>>>(W_ih, W_hh, wtE);
    prep_fc1 <<<1024, 256, 0, stream>>>(fc1_W, wt1);
    prep_fc2 <<< 256, 256, 0, stream>>>(fc2_W, wt2);
    prep_bias<<<   2, 256, 0, stream>>>(b_ih, b_hh, cb);

    rnn_fused<<<Bq / Gq, 1024, 0, stream>>>(x, lens, wtE, wt1, wt2, cb,
                                            fc1_b, fc2_b, (float*)d_out);
}

// Round 2
// 13911.745 us; speedup vs baseline: 1.0283x; 1.0283x over previous
//
#include <hip/hip_runtime.h>

// Problem constants: B=512 T=512 I=128 H=512 C=128 OUT_T=128
#define Bq 512
#define Tq 512
#define Iq 128
#define Hq 512
#define Cq 128
#define OUT_Tq 128
#define Gq 4   // batches per PAIR of blocks

// ---- workspace layout (float offsets) ----
// wt_enc : [160][512][4]   (k transposed; k<128 from W_ih, else W_hh)
// wt_fc1 : [128][512][4]
// wt_fc2 : [128][128][4]
// cbias  : [512]
// flags  : [256] uint32    (pair*2+sub event counters, zeroed each launch)
// gwbh   : [2 par][128 pair][2 sub][1024]  h exchange
// gwbm   : [2 par][128 pair][2 sub][1024]  mid exchange
#define OFF_WTENC 0
#define OFF_WTFC1 327680
#define OFF_WTFC2 589824
#define OFF_CBIAS 655360
#define OFF_FLAGS 655872
#define OFF_GWBH  656128
#define OFF_GWBM  1180416
// total 1704704 floats ~ 6.8 MB

#define ATS(p, v) __hip_atomic_store((p), (v), __ATOMIC_RELAXED, __HIP_MEMORY_SCOPE_AGENT)
#define ATL(p)    __hip_atomic_load((p), __ATOMIC_RELAXED, __HIP_MEMORY_SCOPE_AGENT)

__global__ void prep_enc(const float* __restrict__ W_ih, const float* __restrict__ W_hh,
                         float* __restrict__ wt) {
    int idx = blockIdx.x * 256 + threadIdx.x;           // over 512*640
    if (idx >= 512 * 640) return;
    int n = idx / 640, k = idx % 640;
    float v = (k < Iq) ? W_ih[n * Iq + k] : W_hh[n * Hq + (k - Iq)];
    wt[(k >> 2) * 2048 + n * 4 + (k & 3)] = v;
}

__global__ void prep_fc1(const float* __restrict__ W, float* __restrict__ wt) {
    int idx = blockIdx.x * 256 + threadIdx.x;           // over 512*512
    if (idx >= 512 * 512) return;
    int n = idx >> 9, k = idx & 511;
    wt[(k >> 2) * 2048 + n * 4 + (k & 3)] = W[n * Hq + k];
}

__global__ void prep_fc2(const float* __restrict__ W, float* __restrict__ wt) {
    int idx = blockIdx.x * 256 + threadIdx.x;           // over 128*512
    if (idx >= 128 * 512) return;
    int c = idx >> 9, k = idx & 511;
    wt[(k >> 2) * 512 + c * 4 + (k & 3)] = W[c * Hq + k];
}

__global__ void prep_bias(const float* __restrict__ bih, const float* __restrict__ bhh,
                          float* __restrict__ cb, unsigned* __restrict__ flags) {
    int n = blockIdx.x * 256 + threadIdx.x;
    if (n < Hq) cb[n] = bih[n] + bhh[n];
    if (n < 256) flags[n] = 0u;          // reset pair-sync event counters every launch
}

__device__ __forceinline__ float dot4(float4 w, float4 v) {
    return w.x * v.x + w.y * v.y + w.z * v.z + w.w * v.w;
}

// 256 blocks: pair = blk&127 handles batches pair*4..+3; sub = blk>>7 owns
// neurons [sub*256, sub*256+256). Pair (b, b+128) -> same XCD under %8 mapping.
// Threads: nl = tid&127, kh = tid>>7 (4-way k-split). Each thread: 2 neurons
// (n0=sub*256+nl, n1=n0+128) x 4 batches over its k-window.
// Roles in the post-reduction window: kh0 = reduce+tanh+publish;
// kh1 = spin on partner flag + import partner half; kh2/3 = stage x(t+1).
__global__ void __launch_bounds__(512, 2)
rnn_fused(const float* __restrict__ x, const int* __restrict__ lengths,
          const float* __restrict__ wt_enc, const float* __restrict__ wt_fc1,
          const float* __restrict__ wt_fc2, const float* __restrict__ cbias,
          const float* __restrict__ fc1_b, const float* __restrict__ fc2_b,
          float* __restrict__ gwbh, float* __restrict__ gwbm,
          unsigned* __restrict__ flags,
          float* __restrict__ out) {
    __shared__ __align__(16) float in_s[Gq][Iq + Hq];   // [x_t | h full]  10240 B
    __shared__ __align__(16) float mid_s[Gq][Hq];       //                  8192 B
    __shared__ __align__(16) float sc[4 * 256 * 4];     // [kh][nn][b]     16384 B
    __shared__ __align__(16) float ps[512];             // fc2 partials     2048 B

    const int tid  = threadIdx.x;         // 0..511
    const int pair = blockIdx.x & 127;
    const int sub  = blockIdx.x >> 7;
    const int gb0  = pair * Gq;
    const int nl   = tid & 127;
    const int kh   = tid >> 7;            // 0..3

    const int n0 = sub * 256 + nl;        // global neuron ids owned by this thread
    const int n1 = n0 + 128;

    unsigned* myflag = flags + (pair * 2 + sub);
    unsigned* pflag  = flags + (pair * 2 + (1 - sub));
    const int psub   = 1 - sub;

    const int len0 = lengths[gb0 + 0];
    const int len1 = lengths[gb0 + 1];
    const int len2 = lengths[gb0 + 2];
    const int len3 = lengths[gb0 + 3];
    const int tmax = max(max(len0, len1), max(len2, len3));

    const float cb0 = cbias[n0], cb1 = cbias[n1];

    // ---- init: h = 0 (full), stage x(0) ----
    for (int r = 0; r < 4; ++r) {
        int hf = r * 512 + tid;                       // 0..2047
        in_s[hf >> 9][Iq + (hf & 511)] = 0.f;
    }
    if (tmax > 0 && tid < 256) {
        int b = tid >> 6, i2 = tid & 63;
        *(float2*)&in_s[b][i2 * 2] =
            *(const float2*)&x[((size_t)(gb0 + b) * Tq) * Iq + i2 * 2];
    }
    __syncthreads();

    const float4* We  = (const float4*)wt_enc;        // [160][512] float4
    float4*       sc4 = (float4*)sc;

    // ================= encoder =================
    for (int t = 0; t < tmax; ++t) {
        // prefetch x(t+1) into regs (kh2/3 threads), hides under dot loop
        float2 xr = make_float2(0.f, 0.f);
        int sj = tid - 256, sb = sj >> 6, si = sj & 63;
        if (kh >= 2 && t + 1 < tmax)
            xr = *(const float2*)&x[((size_t)(gb0 + sb) * Tq + (t + 1)) * Iq + si * 2];

        float a00=0,a01=0,a02=0,a03=0,a10=0,a11=0,a12=0,a13=0;
        {
            const float4* wp = We + (kh * 40) * 512 + n0;
            const float4* ip = (const float4*)in_s + kh * 40;   // batch stride 160
#pragma unroll 4
            for (int j = 0; j < 40; ++j) {
                float4 w0 = wp[0];
                float4 w1 = wp[128];
                float4 v0 = ip[0];
                float4 v1 = ip[160];
                float4 v2 = ip[320];
                float4 v3 = ip[480];
                wp += 512; ip += 1;
                a00 += dot4(w0,v0); a01 += dot4(w0,v1); a02 += dot4(w0,v2); a03 += dot4(w0,v3);
                a10 += dot4(w1,v0); a11 += dot4(w1,v1); a12 += dot4(w1,v2); a13 += dot4(w1,v3);
            }
        }
        if (kh) {
            sc4[kh * 256 + nl]       = make_float4(a00, a01, a02, a03);
            sc4[kh * 256 + nl + 128] = make_float4(a10, a11, a12, a13);
        }
        __syncthreads();                               // B1: partials + in_s reads done

        if (kh == 0) {
            float4 q1 = sc4[256 + nl],       q2 = sc4[512 + nl],       q3 = sc4[768 + nl];
            float4 r1 = sc4[256 + nl + 128], r2 = sc4[512 + nl + 128], r3 = sc4[768 + nl + 128];
            float v00 = a00+q1.x+q2.x+q3.x, v01 = a01+q1.y+q2.y+q3.y;
            float v02 = a02+q1.z+q2.z+q3.z, v03 = a03+q1.w+q2.w+q3.w;
            float v10 = a10+r1.x+r2.x+r3.x, v11 = a11+r1.y+r2.y+r3.y;
            float v12 = a12+r1.z+r2.z+r3.z, v13 = a13+r1.w+r2.w+r3.w;
            float* ghw = gwbh + (((size_t)(t & 1) * 128 + pair) * 2 + sub) * 1024;
            float nh;
            nh = (t<len0)? tanhf(v00+cb0) : in_s[0][Iq+n0]; in_s[0][Iq+n0]=nh; ATS(ghw+0*256+nl,     nh);
            nh = (t<len1)? tanhf(v01+cb0) : in_s[1][Iq+n0]; in_s[1][Iq+n0]=nh; ATS(ghw+1*256+nl,     nh);
            nh = (t<len2)? tanhf(v02+cb0) : in_s[2][Iq+n0]; in_s[2][Iq+n0]=nh; ATS(ghw+2*256+nl,     nh);
            nh = (t<len3)? tanhf(v03+cb0) : in_s[3][Iq+n0]; in_s[3][Iq+n0]=nh; ATS(ghw+3*256+nl,     nh);
            nh = (t<len0)? tanhf(v10+cb1) : in_s[0][Iq+n1]; in_s[0][Iq+n1]=nh; ATS(ghw+0*256+nl+128, nh);
            nh = (t<len1)? tanhf(v11+cb1) : in_s[1][Iq+n1]; in_s[1][Iq+n1]=nh; ATS(ghw+1*256+nl+128, nh);
            nh = (t<len2)? tanhf(v12+cb1) : in_s[2][Iq+n1]; in_s[2][Iq+n1]=nh; ATS(ghw+2*256+nl+128, nh);
            nh = (t<len3)? tanhf(v13+cb1) : in_s[3][Iq+n1]; in_s[3][Iq+n1]=nh; ATS(ghw+3*256+nl+128, nh);
            asm volatile("s_waitcnt vmcnt(0)" ::: "memory");   // stores at coherence point
            if ((tid & 63) == 0)
                __hip_atomic_fetch_add(myflag, 1u, __ATOMIC_RELEASE, __HIP_MEMORY_SCOPE_AGENT);
        } else if (kh == 1) {
            unsigned tgt = 2u * (unsigned)(t + 1);             // 2 waves per event
            while (ATL(pflag) < tgt) __builtin_amdgcn_s_sleep(2);
            __builtin_amdgcn_sched_barrier(0);
            const float* ghr = gwbh + (((size_t)(t & 1) * 128 + pair) * 2 + psub) * 1024;
            int pb = psub * 256;
#pragma unroll
            for (int b = 0; b < 4; ++b) {
                in_s[b][Iq + pb + nl]       = ATL(ghr + b * 256 + nl);
                in_s[b][Iq + pb + nl + 128] = ATL(ghr + b * 256 + nl + 128);
            }
        } else {
            if (t + 1 < tmax) *(float2*)&in_s[sb][si * 2] = xr;
        }
        __syncthreads();                               // B2: in_s = [x(t+1), h(t) full]
    }

    // ================= decoder =================
    const float4* Wd = We + 32 * 512;                  // W_hh^T rows (h part)
    const float4* W1 = (const float4*)wt_fc1;
    const float4* W2 = (const float4*)wt_fc2;
    const float f1b0 = fc1_b[n0], f1b1 = fc1_b[n1];
    const int c6 = tid & 63, bq = (tid >> 6) & 3, kh2 = tid >> 8;
    const float f2b = fc2_b[sub * 64 + c6];
    const unsigned base = 2u * (unsigned)tmax;

    for (int t = 0; t < OUT_Tq; ++t) {
        const size_t par = (size_t)(t & 1);
        // ---- P1: nh = tanh(cbias + h @ W_hh^T) ----
        float a00=0,a01=0,a02=0,a03=0,a10=0,a11=0,a12=0,a13=0;
        {
            const float4* wp = Wd + (kh * 32) * 512 + n0;
            const float4* hp = (const float4*)&in_s[0][Iq] + kh * 32;
#pragma unroll 4
            for (int j = 0; j < 32; ++j) {
                float4 w0 = wp[0];
                float4 w1 = wp[128];
                float4 v0 = hp[0];
                float4 v1 = hp[160];
                float4 v2 = hp[320];
                float4 v3 = hp[480];
                wp += 512; hp += 1;
                a00 += dot4(w0,v0); a01 += dot4(w0,v1); a02 += dot4(w0,v2); a03 += dot4(w0,v3);
                a10 += dot4(w1,v0); a11 += dot4(w1,v1); a12 += dot4(w1,v2); a13 += dot4(w1,v3);
            }
        }
        if (kh) {
            sc4[kh * 256 + nl]       = make_float4(a00, a01, a02, a03);
            sc4[kh * 256 + nl + 128] = make_float4(a10, a11, a12, a13);
        }
        __syncthreads();                               // D-B1
        if (kh == 0) {
            float4 q1 = sc4[256 + nl],       q2 = sc4[512 + nl],       q3 = sc4[768 + nl];
            float4 r1 = sc4[256 + nl + 128], r2 = sc4[512 + nl + 128], r3 = sc4[768 + nl + 128];
            float* ghw = gwbh + ((par * 128 + pair) * 2 + sub) * 1024;
            float nh;
            nh = tanhf(a00+q1.x+q2.x+q3.x + cb0); in_s[0][Iq+n0]=nh; ATS(ghw+0*256+nl,     nh);
            nh = tanhf(a01+q1.y+q2.y+q3.y + cb0); in_s[1][Iq+n0]=nh; ATS(ghw+1*256+nl,     nh);
            nh = tanhf(a02+q1.z+q2.z+q3.z + cb0); in_s[2][Iq+n0]=nh; ATS(ghw+2*256+nl,     nh);
            nh = tanhf(a03+q1.w+q2.w+q3.w + cb0); in_s[3][Iq+n0]=nh; ATS(ghw+3*256+nl,     nh);
            nh = tanhf(a10+r1.x+r2.x+r3.x + cb1); in_s[0][Iq+n1]=nh; ATS(ghw+0*256+nl+128, nh);
            nh = tanhf(a11+r1.y+r2.y+r3.y + cb1); in_s[1][Iq+n1]=nh; ATS(ghw+1*256+nl+128, nh);
            nh = tanhf(a12+r1.z+r2.z+r3.z + cb1); in_s[2][Iq+n1]=nh; ATS(ghw+2*256+nl+128, nh);
            nh = tanhf(a13+r1.w+r2.w+r3.w + cb1); in_s[3][Iq+n1]=nh; ATS(ghw+3*256+nl+128, nh);
            asm volatile("s_waitcnt vmcnt(0)" ::: "memory");
            if ((tid & 63) == 0)
                __hip_atomic_fetch_add(myflag, 1u, __ATOMIC_RELEASE, __HIP_MEMORY_SCOPE_AGENT);
        } else if (kh == 1) {
            unsigned tgt = base + 4u * (unsigned)t + 2u;
            while (ATL(pflag) < tgt) __builtin_amdgcn_s_sleep(2);
            __builtin_amdgcn_sched_barrier(0);
            const float* ghr = gwbh + ((par * 128 + pair) * 2 + psub) * 1024;
            int pb = psub * 256;
#pragma unroll
            for (int b = 0; b < 4; ++b) {
                in_s[b][Iq + pb + nl]       = ATL(ghr + b * 256 + nl);
                in_s[b][Iq + pb + nl + 128] = ATL(ghr + b * 256 + nl + 128);
            }
        }
        __syncthreads();                               // D-B2: nh full
        // ---- P2: mid = relu(nh @ fc1^T + fc1_b) ----
        a00=0;a01=0;a02=0;a03=0;a10=0;a11=0;a12=0;a13=0;
        {
            const float4* wp = W1 + (kh * 32) * 512 + n0;
            const float4* hp = (const float4*)&in_s[0][Iq] + kh * 32;
#pragma unroll 4
            for (int j = 0; j < 32; ++j) {
                float4 w0 = wp[0];
                float4 w1 = wp[128];
                float4 v0 = hp[0];
                float4 v1 = hp[160];
                float4 v2 = hp[320];
                float4 v3 = hp[480];
                wp += 512; hp += 1;
                a00 += dot4(w0,v0); a01 += dot4(w0,v1); a02 += dot4(w0,v2); a03 += dot4(w0,v3);
                a10 += dot4(w1,v0); a11 += dot4(w1,v1); a12 += dot4(w1,v2); a13 += dot4(w1,v3);
            }
        }
        if (kh) {
            sc4[kh * 256 + nl]       = make_float4(a00, a01, a02, a03);
            sc4[kh * 256 + nl + 128] = make_float4(a10, a11, a12, a13);
        }
        __syncthreads();                               // D-B3
        if (kh == 0) {
            float4 q1 = sc4[256 + nl],       q2 = sc4[512 + nl],       q3 = sc4[768 + nl];
            float4 r1 = sc4[256 + nl + 128], r2 = sc4[512 + nl + 128], r3 = sc4[768 + nl + 128];
            float* gmw = gwbm + ((par * 128 + pair) * 2 + sub) * 1024;
            float m;
            m = fmaxf(a00+q1.x+q2.x+q3.x + f1b0, 0.f); mid_s[0][n0]=m; ATS(gmw+0*256+nl,     m);
            m = fmaxf(a01+q1.y+q2.y+q3.y + f1b0, 0.f); mid_s[1][n0]=m; ATS(gmw+1*256+nl,     m);
            m = fmaxf(a02+q1.z+q2.z+q3.z + f1b0, 0.f); mid_s[2][n0]=m; ATS(gmw+2*256+nl,     m);
            m = fmaxf(a03+q1.w+q2.w+q3.w + f1b0, 0.f); mid_s[3][n0]=m; ATS(gmw+3*256+nl,     m);
            m = fmaxf(a10+r1.x+r2.x+r3.x + f1b1, 0.f); mid_s[0][n1]=m; ATS(gmw+0*256+nl+128, m);
            m = fmaxf(a11+r1.y+r2.y+r3.y + f1b1, 0.f); mid_s[1][n1]=m; ATS(gmw+1*256+nl+128, m);
            m = fmaxf(a12+r1.z+r2.z+r3.z + f1b1, 0.f); mid_s[2][n1]=m; ATS(gmw+2*256+nl+128, m);
            m = fmaxf(a13+r1.w+r2.w+r3.w + f1b1, 0.f); mid_s[3][n1]=m; ATS(gmw+3*256+nl+128, m);
            asm volatile("s_waitcnt vmcnt(0)" ::: "memory");
            if ((tid & 63) == 0)
                __hip_atomic_fetch_add(myflag, 1u, __ATOMIC_RELEASE, __HIP_MEMORY_SCOPE_AGENT);
        } else if (kh == 1) {
            unsigned tgt = base + 4u * (unsigned)t + 4u;
            while (ATL(pflag) < tgt) __builtin_amdgcn_s_sleep(2);
            __builtin_amdgcn_sched_barrier(0);
            const float* gmr = gwbm + ((par * 128 + pair) * 2 + psub) * 1024;
            int pb = psub * 256;
#pragma unroll
            for (int b = 0; b < 4; ++b) {
                mid_s[b][pb + nl]       = ATL(gmr + b * 256 + nl);
                mid_s[b][pb + nl + 128] = ATL(gmr + b * 256 + nl + 128);
            }
        }
        __syncthreads();                               // D-B4: mid full
        // ---- P3: out = mid @ fc2^T + fc2_b  (c-split across pair, k-split x2) ----
        float ao = 0.f;
        {
            const float4* wp = W2 + (kh2 * 64) * 128 + sub * 64 + c6;
            const float4* mp = (const float4*)&mid_s[bq][0] + kh2 * 64;
#pragma unroll 4
            for (int j = 0; j < 64; ++j) {
                ao += dot4(wp[0], mp[0]);
                wp += 128; mp += 1;
            }
        }
        ps[tid] = ao;
        __syncthreads();                               // D-B5
        if (tid < 256)
            out[((size_t)(gb0 + bq) * OUT_Tq + t) * Cq + sub * 64 + c6] =
                ps[tid] + ps[tid + 256] + f2b;
        // next ps write happens after D-B4(t+1) -> no trailing barrier needed
    }
}

extern "C" void kernel_launch(void* const* d_in, const int* in_sizes, int n_in,
                              void* d_out, int out_size, void* d_ws, size_t ws_size,
                              hipStream_t stream) {
    const float* x      = (const float*)d_in[0];
    const int*   lens   = (const int*)d_in[1];
    // d_in[2] = out_lengths (constant 128, hardcoded)
    const float* W_ih   = (const float*)d_in[3];
    const float* W_hh   = (const float*)d_in[4];
    const float* b_ih   = (const float*)d_in[5];
    const float* b_hh   = (const float*)d_in[6];
    const float* fc1_W  = (const float*)d_in[7];
    const float* fc1_b  = (const float*)d_in[8];
    const float* fc2_W  = (const float*)d_in[9];
    const float* fc2_b  = (const float*)d_in[10];

    float* ws    = (float*)d_ws;
    float* wtE   = ws + OFF_WTENC;
    float* wt1   = ws + OFF_WTFC1;
    float* wt2   = ws + OFF_WTFC2;
    float* cb    = ws + OFF_CBIAS;
    unsigned* fl = (unsigned*)(ws + OFF_FLAGS);
    float* gwbh  = ws + OFF_GWBH;
    float* gwbm  = ws + OFF_GWBM;

    prep_enc <<<1280, 256, 0, stream>>>(W_ih, W_hh, wtE);
    prep_fc1 <<<1024, 256, 0, stream>>>(fc1_W, wt1);
    prep_fc2 <<< 256, 256, 0, stream>>>(fc2_W, wt2);
    prep_bias<<<   2, 256, 0, stream>>>(b_ih, b_hh, cb, fl);

    rnn_fused<<<256, 512, 0, stream>>>(x, lens, wtE, wt1, wt2, cb,
                                       fc1_b, fc2_b, gwbh, gwbm, fl, (float*)d_out);
}

// Round 3
// 7352.531 us; speedup vs baseline: 1.9456x; 1.8921x over previous
//
#include <hip/hip_runtime.h>

// Problem constants: B=512 T=512 I=128 H=512 C=128 OUT_T=128
#define Bq 512
#define Tq 512
#define Iq 128
#define Hq 512
#define Cq 128
#define OUT_Tq 128
#define Gq 4   // batches per block

// ---- workspace layout (BYTE offsets) ----
// wtE : 640*512 f16  [k>>3][n][k&7]   655360 B
// wt1 : 512*512 f16  [k>>3][n][k&7]   524288 B
// wt2 : 512*128 f16  [k>>3][c][k&7]   131072 B
// cb  : 512 f32                          2048 B
#define OFFB_WTE 0
#define OFFB_WT1 655360
#define OFFB_WT2 1179648
#define OFFB_CB  1310720

typedef _Float16 h2_t __attribute__((ext_vector_type(2)));

__device__ __forceinline__ float fdot2f(unsigned w, unsigned v, float c) {
#if __has_builtin(__builtin_amdgcn_fdot2)
    return __builtin_amdgcn_fdot2(__builtin_bit_cast(h2_t, w),
                                  __builtin_bit_cast(h2_t, v), c, false);
#else
    union { unsigned u; _Float16 h[2]; } A, B; A.u = w; B.u = v;
    return c + (float)A.h[0] * (float)B.h[0] + (float)A.h[1] * (float)B.h[1];
#endif
}

__global__ void prep_enc(const float* __restrict__ W_ih, const float* __restrict__ W_hh,
                         _Float16* __restrict__ wt) {
    int idx = blockIdx.x * 256 + threadIdx.x;           // over 512*640
    if (idx >= 512 * 640) return;
    int n = idx / 640, k = idx % 640;
    float v = (k < Iq) ? W_ih[n * Iq + k] : W_hh[n * Hq + (k - Iq)];
    wt[(((k >> 3) * 512) + n) * 8 + (k & 7)] = (_Float16)v;
}

__global__ void prep_fc1(const float* __restrict__ W, _Float16* __restrict__ wt) {
    int idx = blockIdx.x * 256 + threadIdx.x;           // over 512*512
    if (idx >= 512 * 512) return;
    int n = idx >> 9, k = idx & 511;
    wt[(((k >> 3) * 512) + n) * 8 + (k & 7)] = (_Float16)W[n * Hq + k];
}

__global__ void prep_fc2(const float* __restrict__ W, _Float16* __restrict__ wt) {
    int idx = blockIdx.x * 256 + threadIdx.x;           // over 128*512
    if (idx >= 128 * 512) return;
    int c = idx >> 9, k = idx & 511;
    wt[(((k >> 3) * 128) + c) * 8 + (k & 7)] = (_Float16)W[c * Hq + k];
}

__global__ void prep_bias(const float* __restrict__ bih, const float* __restrict__ bhh,
                          float* __restrict__ cb) {
    int n = blockIdx.x * 256 + threadIdx.x;
    if (n < Hq) cb[n] = bih[n] + bhh[n];
}

// R0 skeleton (128 blocks x 512 threads, proven barrier structure), fp16 data path.
// Per enc step per block: 0.655 MB weight stream (was 1.31 MB) + 1280 dot2/thread
// (was 2560 FMA). fp32 accumulate via v_dot2_f32_f16; tanh/bias/output fp32.
__global__ void __launch_bounds__(512, 2)
rnn_fused(const float* __restrict__ x, const int* __restrict__ lengths,
          const uint4* __restrict__ WE, const uint4* __restrict__ W1,
          const uint4* __restrict__ W2, const float* __restrict__ cbias,
          const float* __restrict__ fc1_b, const float* __restrict__ fc2_b,
          float* __restrict__ out) {
    __shared__ __align__(16) unsigned in2_s[Gq][320];   // f16 pairs: [x(128) | h(512)]
    __shared__ __align__(16) unsigned mid2_s[Gq][256];  // f16 pairs: mid(512)

    const int tid = threadIdx.x;          // 0..511
    const int n = tid;
    const int gb0 = blockIdx.x * Gq;

    const int len0 = lengths[gb0 + 0];
    const int len1 = lengths[gb0 + 1];
    const int len2 = lengths[gb0 + 2];
    const int len3 = lengths[gb0 + 3];
    const int tmax = max(max(len0, len1), max(len2, len3));

    const float cb = cbias[n];
    _Float16* inh = (_Float16*)in2_s;     // [b*640 + k]

    // h = 0
    for (int b = 0; b < Gq; ++b) inh[b * 640 + 128 + n] = (_Float16)0.f;
    __syncthreads();

    const uint4* I4 = (const uint4*)in2_s;   // [b*80 + j], j = 8-k-elem chunk

    // ---------------- encoder ----------------
    for (int t = 0; t < tmax; ++t) {
        {   // stage x_t as f16 (4 batches x 128)
            int b = tid >> 7, i = tid & 127;
            inh[b * 640 + i] =
                (_Float16)x[(size_t)(gb0 + b) * Tq * Iq + (size_t)t * Iq + i];
        }
        __syncthreads();
        float aA0=0,aB0=0,aA1=0,aB1=0,aA2=0,aB2=0,aA3=0,aB3=0;
#pragma unroll 8
        for (int j = 0; j < 80; ++j) {
            uint4 w  = WE[j * 512 + n];                  // 8 f16 weights, coalesced
            uint4 v0 = I4[j];                            // LDS broadcast, 8 f16
            uint4 v1 = I4[80 + j];
            uint4 v2 = I4[160 + j];
            uint4 v3 = I4[240 + j];
            aA0 = fdot2f(w.x, v0.x, aA0); aA0 = fdot2f(w.y, v0.y, aA0);
            aB0 = fdot2f(w.z, v0.z, aB0); aB0 = fdot2f(w.w, v0.w, aB0);
            aA1 = fdot2f(w.x, v1.x, aA1); aA1 = fdot2f(w.y, v1.y, aA1);
            aB1 = fdot2f(w.z, v1.z, aB1); aB1 = fdot2f(w.w, v1.w, aB1);
            aA2 = fdot2f(w.x, v2.x, aA2); aA2 = fdot2f(w.y, v2.y, aA2);
            aB2 = fdot2f(w.z, v2.z, aB2); aB2 = fdot2f(w.w, v2.w, aB2);
            aA3 = fdot2f(w.x, v3.x, aA3); aA3 = fdot2f(w.y, v3.y, aA3);
            aB3 = fdot2f(w.z, v3.z, aB3); aB3 = fdot2f(w.w, v3.w, aB3);
        }
        float nh0 = tanhf(aA0 + aB0 + cb);
        float nh1 = tanhf(aA1 + aB1 + cb);
        float nh2 = tanhf(aA2 + aB2 + cb);
        float nh3 = tanhf(aA3 + aB3 + cb);
        __syncthreads();    // all reads of in2_s done
        if (t < len0) inh[0 * 640 + 128 + n] = (_Float16)nh0;
        if (t < len1) inh[1 * 640 + 128 + n] = (_Float16)nh1;
        if (t < len2) inh[2 * 640 + 128 + n] = (_Float16)nh2;
        if (t < len3) inh[3 * 640 + 128 + n] = (_Float16)nh3;
        // next iter: x-stage writes disjoint region; top barrier publishes both
    }
    __syncthreads();

    // ---------------- decoder ----------------
    const float f1b = fc1_b[n];
    const int bq = tid >> 7, c = tid & 127;
    const float f2b = fc2_b[c];
    _Float16* midh = (_Float16*)mid2_s;      // [b*512 + n]
    const uint4* M4 = (const uint4*)mid2_s;  // [b*64 + j]
    const uint4* Wd = WE + 16 * 512;         // W_hh^T part (k = 128..639)

    for (int t = 0; t < OUT_Tq; ++t) {
        // P1: nh = tanh(cbias + h @ W_hh^T)
        float aA0=0,aB0=0,aA1=0,aB1=0,aA2=0,aB2=0,aA3=0,aB3=0;
#pragma unroll 8
        for (int j = 0; j < 64; ++j) {
            uint4 w  = Wd[j * 512 + n];
            uint4 v0 = I4[16 + j];
            uint4 v1 = I4[96 + j];
            uint4 v2 = I4[176 + j];
            uint4 v3 = I4[256 + j];
            aA0 = fdot2f(w.x, v0.x, aA0); aA0 = fdot2f(w.y, v0.y, aA0);
            aB0 = fdot2f(w.z, v0.z, aB0); aB0 = fdot2f(w.w, v0.w, aB0);
            aA1 = fdot2f(w.x, v1.x, aA1); aA1 = fdot2f(w.y, v1.y, aA1);
            aB1 = fdot2f(w.z, v1.z, aB1); aB1 = fdot2f(w.w, v1.w, aB1);
            aA2 = fdot2f(w.x, v2.x, aA2); aA2 = fdot2f(w.y, v2.y, aA2);
            aB2 = fdot2f(w.z, v2.z, aB2); aB2 = fdot2f(w.w, v2.w, aB2);
            aA3 = fdot2f(w.x, v3.x, aA3); aA3 = fdot2f(w.y, v3.y, aA3);
            aB3 = fdot2f(w.z, v3.z, aB3); aB3 = fdot2f(w.w, v3.w, aB3);
        }
        float nh0 = tanhf(aA0 + aB0 + cb);
        float nh1 = tanhf(aA1 + aB1 + cb);
        float nh2 = tanhf(aA2 + aB2 + cb);
        float nh3 = tanhf(aA3 + aB3 + cb);
        __syncthreads();    // P1 reads of h done
        inh[0 * 640 + 128 + n] = (_Float16)nh0;
        inh[1 * 640 + 128 + n] = (_Float16)nh1;
        inh[2 * 640 + 128 + n] = (_Float16)nh2;
        inh[3 * 640 + 128 + n] = (_Float16)nh3;
        __syncthreads();    // new h published
        // P2: mid = relu(nh @ fc1^T + fc1_b)
        aA0=0;aB0=0;aA1=0;aB1=0;aA2=0;aB2=0;aA3=0;aB3=0;
#pragma unroll 8
        for (int j = 0; j < 64; ++j) {
            uint4 w  = W1[j * 512 + n];
            uint4 v0 = I4[16 + j];
            uint4 v1 = I4[96 + j];
            uint4 v2 = I4[176 + j];
            uint4 v3 = I4[256 + j];
            aA0 = fdot2f(w.x, v0.x, aA0); aA0 = fdot2f(w.y, v0.y, aA0);
            aB0 = fdot2f(w.z, v0.z, aB0); aB0 = fdot2f(w.w, v0.w, aB0);
            aA1 = fdot2f(w.x, v1.x, aA1); aA1 = fdot2f(w.y, v1.y, aA1);
            aB1 = fdot2f(w.z, v1.z, aB1); aB1 = fdot2f(w.w, v1.w, aB1);
            aA2 = fdot2f(w.x, v2.x, aA2); aA2 = fdot2f(w.y, v2.y, aA2);
            aB2 = fdot2f(w.z, v2.z, aB2); aB2 = fdot2f(w.w, v2.w, aB2);
            aA3 = fdot2f(w.x, v3.x, aA3); aA3 = fdot2f(w.y, v3.y, aA3);
            aB3 = fdot2f(w.z, v3.z, aB3); aB3 = fdot2f(w.w, v3.w, aB3);
        }
        // prior iter's P3 mid-reads finished before its trailing barrier -> safe
        midh[0 * 512 + n] = (_Float16)fmaxf(aA0 + aB0 + f1b, 0.f);
        midh[1 * 512 + n] = (_Float16)fmaxf(aA1 + aB1 + f1b, 0.f);
        midh[2 * 512 + n] = (_Float16)fmaxf(aA2 + aB2 + f1b, 0.f);
        midh[3 * 512 + n] = (_Float16)fmaxf(aA3 + aB3 + f1b, 0.f);
        __syncthreads();    // mid published
        // P3: out = mid @ fc2^T + fc2_b   (thread -> (bq, c))
        float ao = 0.f, ao2 = 0.f;
#pragma unroll 8
        for (int j = 0; j < 64; ++j) {
            uint4 w = W2[j * 128 + c];
            uint4 m = M4[bq * 64 + j];
            ao  = fdot2f(w.x, m.x, ao);  ao  = fdot2f(w.y, m.y, ao);
            ao2 = fdot2f(w.z, m.z, ao2); ao2 = fdot2f(w.w, m.w, ao2);
        }
        out[((size_t)(gb0 + bq) * OUT_Tq + t) * Cq + c] = ao + ao2 + f2b;
        __syncthreads();    // mid reads done before next-iter writes
    }
}

extern "C" void kernel_launch(void* const* d_in, const int* in_sizes, int n_in,
                              void* d_out, int out_size, void* d_ws, size_t ws_size,
                              hipStream_t stream) {
    const float* x      = (const float*)d_in[0];
    const int*   lens   = (const int*)d_in[1];
    // d_in[2] = out_lengths (constant 128, hardcoded)
    const float* W_ih   = (const float*)d_in[3];
    const float* W_hh   = (const float*)d_in[4];
    const float* b_ih   = (const float*)d_in[5];
    const float* b_hh   = (const float*)d_in[6];
    const float* fc1_W  = (const float*)d_in[7];
    const float* fc1_b  = (const float*)d_in[8];
    const float* fc2_W  = (const float*)d_in[9];
    const float* fc2_b  = (const float*)d_in[10];

    char* wsb = (char*)d_ws;
    _Float16* wtE = (_Float16*)(wsb + OFFB_WTE);
    _Float16* wt1 = (_Float16*)(wsb + OFFB_WT1);
    _Float16* wt2 = (_Float16*)(wsb + OFFB_WT2);
    float*    cb  = (float*)   (wsb + OFFB_CB);

    prep_enc <<<1280, 256, 0, stream>>>(W_ih, W_hh, wtE);
    prep_fc1 <<<1024, 256, 0, stream>>>(fc1_W, wt1);
    prep_fc2 <<< 256, 256, 0, stream>>>(fc2_W, wt2);
    prep_bias<<<   2, 256, 0, stream>>>(b_ih, b_hh, cb);

    rnn_fused<<<Bq / Gq, 512, 0, stream>>>(x, lens,
                                           (const uint4*)wtE, (const uint4*)wt1,
                                           (const uint4*)wt2, cb,
                                           fc1_b, fc2_b, (float*)d_out);
}